// Round 10
// baseline (480.841 us; speedup 1.0000x reference)
//
#include <hip/hip_runtime.h>

#define BB 4096
#define AA_ 32
#define OBSD 128
#define HIDD 256
#define MSGD 64
#define NHH 4
#define DHH 16
#define NACTD 16
#define NT 512

// workspace pre-split weight layout (element offsets; hi at [i], lo at [WS_TOTAL+i])
// WM=2 reads ONLY hi (bf16 weights); lo kept for WM=1-compat layout.
#define OFF_WLOCAL 0
#define OFF_WINTER 32768
#define OFF_WINTRA 40960
#define OFF_WQKV   49152
#define OFF_WO     98304
#define OFF_W1     114688
#define OFF_W2     212992
#define OFF_WA     278528
#define OFF_WHEAD  282624   // augmented head [32][256]: rows 0-15 Wa, 16 Wv, 17-31 zero
#define WS_TOTAL   290816

// LDS arena (bytes), total 99328 -> 1 block/CU (gfx950 allows >64KB static LDS).
// M=64: rows 0-31 = batch b0, rows 32-63 = batch b0+1.
//  L_LB 0      localb [64][264] 33792  (h2 in P5->P6)
//  L_IO 33792  iobs [64][72] 9216      (alog [64][18]f32 in P6)
//  L_IE 43008  intra_e [64][72]        (nobs net2/3 | hb [64][264] P4->P5, 43008..76800)
//  L_NE 52224  inter_e [64][72]
//  L_QK 61440  qk [64][136] (q 0-63, k 64-127, 128-135 ZEROED pad) | xh (P1)
//  L_VT 78848  vT [2][64][40] 10240    (xl [64][136] in P1, WM=1 only)
//  L_AT 89088  atto [64][72] 9216
//  L_SC 98304  pooled_hi[128]u16, pooled_lo[128]u16, plog[64]f32, pscore[64]f32
#define L_LB 0
#define L_IO 33792
#define L_IE 43008
#define L_NE 52224
#define L_QK 61440
#define L_VT 78848
#define L_AT 89088
#define L_SC 98304
#define SMEM_SZ 99328

typedef unsigned short u16;
typedef unsigned int u32;
typedef __attribute__((ext_vector_type(8))) short bf16x8;
typedef __attribute__((ext_vector_type(4))) float f32x4;

#define MFMA16(a, b, c) __builtin_amdgcn_mfma_f32_16x16x32_bf16((a), (b), (c), 0, 0, 0)

__device__ __forceinline__ float b2f(u16 s) { return __uint_as_float((u32)s << 16); }
__device__ __forceinline__ u16 f2b(float f) {
    u32 u = __float_as_uint(f);
    u += 0x7FFFu + ((u >> 16) & 1u);   // round-to-nearest-even
    return (u16)(u >> 16);
}
__device__ __forceinline__ float tof(float x) { return x; }
__device__ __forceinline__ float tof(u16 x) { return b2f(x); }
template<typename T> __device__ __forceinline__ T fromf(float v);
template<> __device__ __forceinline__ float fromf<float>(float v) { return v; }
template<> __device__ __forceinline__ u16 fromf<u16>(float v) { return f2b(v); }

__device__ __forceinline__ bf16x8 bzero8() { bf16x8 v = {0,0,0,0,0,0,0,0}; return v; }

// fast tanh: err ~1e-6, far below bf16 storage quantum
__device__ __forceinline__ float fast_tanh(float x) {
    float ax = fabsf(x);
    float e = __expf(-2.f * ax);
    float t = (1.f - e) * __builtin_amdgcn_rcpf(1.f + e);
    return copysignf(t, x);
}

// Weight fragment loader. WM: 0 = bf16 direct (T=u16), 1 = f32 self-split (T=float,
// hi/lo 2-MFMA path), 2 = pre-split bf16 hi ONLY from workspace (1 MFMA).
template<int WM, typename T>
__device__ __forceinline__ void loadW(const T* Wf, const u16* Whi, const u16* Wlo,
                                      int ldw, int n, int k, bf16x8& bh, bf16x8& bl) {
    if constexpr (WM == 0) {
        bh = *(const bf16x8*)((const u16*)Wf + (size_t)n * ldw + k);
    } else if constexpr (WM == 2) {
        bh = *(const bf16x8*)(Whi + (size_t)n * ldw + k);
        (void)Wlo;
    } else {
        const float* p = (const float*)Wf + (size_t)n * ldw + k;
        f32x4 f0 = *(const f32x4*)(p);
        f32x4 f1 = *(const f32x4*)(p + 4);
#pragma unroll
        for (int j = 0; j < 8; j++) {
            float fv = (j < 4) ? f0[j] : f1[j - 4];
            u16 h = f2b(fv);
            bh[j] = (short)h;
            bl[j] = (short)f2b(fv - b2f(h));
        }
    }
}

// O[0..63][0..N) = act(X[64xK] @ W^T + bias); 4 row-tiles per weight fragment.
template<int N, int K, int ACT, int WM, typename T>
__device__ __forceinline__ void mdense64(const u16* X, int ldx,
                                         const T* Wf, const u16* Whi, const u16* Wlo,
                                         const T* bias, u16* O, int ldo) {
    const int tid = threadIdx.x;
    const int wv = tid >> 6, lo16 = tid & 15, hi = (tid & 63) >> 4;
#pragma unroll 1
    for (int nt = wv; nt < N / 16; nt += 8) {
        f32x4 acc0 = {0.f,0.f,0.f,0.f}, acc1 = {0.f,0.f,0.f,0.f};
        f32x4 acc2 = {0.f,0.f,0.f,0.f}, acc3 = {0.f,0.f,0.f,0.f};
#pragma unroll
        for (int k0 = 0; k0 < K; k0 += 32) {
            bf16x8 bh, bl;
            loadW<WM>(Wf, Whi, Wlo, K, nt * 16 + lo16, k0 + hi * 8, bh, bl);
            bf16x8 a0 = *(const bf16x8*)(X + lo16 * ldx + k0 + hi * 8);
            bf16x8 a1 = *(const bf16x8*)(X + (16 + lo16) * ldx + k0 + hi * 8);
            bf16x8 a2 = *(const bf16x8*)(X + (32 + lo16) * ldx + k0 + hi * 8);
            bf16x8 a3 = *(const bf16x8*)(X + (48 + lo16) * ldx + k0 + hi * 8);
            acc0 = MFMA16(a0, bh, acc0);
            acc1 = MFMA16(a1, bh, acc1);
            acc2 = MFMA16(a2, bh, acc2);
            acc3 = MFMA16(a3, bh, acc3);
            if constexpr (WM == 1) {
                acc0 = MFMA16(a0, bl, acc0);
                acc1 = MFMA16(a1, bl, acc1);
                acc2 = MFMA16(a2, bl, acc2);
                acc3 = MFMA16(a3, bl, acc3);
            }
        }
        float bb = tof(bias[nt * 16 + lo16]);
#pragma unroll
        for (int r = 0; r < 4; r++) {
            float v0 = acc0[r] + bb, v1 = acc1[r] + bb, v2 = acc2[r] + bb, v3 = acc3[r] + bb;
            if (ACT) { v0 = fast_tanh(v0); v1 = fast_tanh(v1); v2 = fast_tanh(v2); v3 = fast_tanh(v3); }
            O[(hi * 4 + r) * ldo + nt * 16 + lo16] = f2b(v0);
            O[(16 + hi * 4 + r) * ldo + nt * 16 + lo16] = f2b(v1);
            O[(32 + hi * 4 + r) * ldo + nt * 16 + lo16] = f2b(v2);
            O[(48 + hi * 4 + r) * ldo + nt * 16 + lo16] = f2b(v3);
        }
    }
}

// QKV pass for one net (M=64): q,k -> qk[row][col]; v -> per-batch transposed vT.
template<int WM, typename T>
__device__ __forceinline__ void qkv_pass(int net, const u16* xe,
                                         const T* Wqkv, const T* bqkv,
                                         const u16* wsh, const u16* wsl,
                                         u16* qk, u16* vT) {
    const int tid = threadIdx.x;
    const int wv = tid >> 6, lo16 = tid & 15, hi = (tid & 63) >> 4;
    const T* Wq = Wqkv + (size_t)net * 192 * MSGD;
    const T* bq_ = bqkv + (size_t)net * 192;
    const u16* Whi = (WM == 2) ? wsh + OFF_WQKV + net * 192 * MSGD : nullptr;
    const u16* Wlo = (WM == 2) ? wsl + OFF_WQKV + net * 192 * MSGD : nullptr;
#pragma unroll 1
    for (int nt = wv; nt < 12; nt += 8) {
        f32x4 acc0 = {0.f,0.f,0.f,0.f}, acc1 = {0.f,0.f,0.f,0.f};
        f32x4 acc2 = {0.f,0.f,0.f,0.f}, acc3 = {0.f,0.f,0.f,0.f};
#pragma unroll
        for (int k0 = 0; k0 < 64; k0 += 32) {
            bf16x8 bh, bl;
            loadW<WM>(Wq, Whi, Wlo, 64, nt * 16 + lo16, k0 + hi * 8, bh, bl);
            bf16x8 a0 = *(const bf16x8*)(xe + lo16 * 72 + k0 + hi * 8);
            bf16x8 a1 = *(const bf16x8*)(xe + (16 + lo16) * 72 + k0 + hi * 8);
            bf16x8 a2 = *(const bf16x8*)(xe + (32 + lo16) * 72 + k0 + hi * 8);
            bf16x8 a3 = *(const bf16x8*)(xe + (48 + lo16) * 72 + k0 + hi * 8);
            acc0 = MFMA16(a0, bh, acc0);
            acc1 = MFMA16(a1, bh, acc1);
            acc2 = MFMA16(a2, bh, acc2);
            acc3 = MFMA16(a3, bh, acc3);
            if constexpr (WM == 1) {
                acc0 = MFMA16(a0, bl, acc0);
                acc1 = MFMA16(a1, bl, acc1);
                acc2 = MFMA16(a2, bl, acc2);
                acc3 = MFMA16(a3, bl, acc3);
            }
        }
        float bb = tof(bq_[nt * 16 + lo16]);
        if (nt < 8) {
#pragma unroll
            for (int r = 0; r < 4; r++) {
                qk[(hi * 4 + r) * 136 + nt * 16 + lo16] = f2b(acc0[r] + bb);
                qk[(16 + hi * 4 + r) * 136 + nt * 16 + lo16] = f2b(acc1[r] + bb);
                qk[(32 + hi * 4 + r) * 136 + nt * 16 + lo16] = f2b(acc2[r] + bb);
                qk[(48 + hi * 4 + r) * 136 + nt * 16 + lo16] = f2b(acc3[r] + bb);
            }
        } else {
            const int d = (nt - 8) * 16 + lo16;
#pragma unroll
            for (int r = 0; r < 4; r++) {
                vT[d * 40 + hi * 4 + r] = f2b(acc0[r] + bb);               // batch0
                vT[d * 40 + 16 + hi * 4 + r] = f2b(acc1[r] + bb);
                vT[2560 + d * 40 + hi * 4 + r] = f2b(acc2[r] + bb);        // batch1
                vT[2560 + d * 40 + 16 + hi * 4 + r] = f2b(acc3[r] + bb);
            }
        }
    }
}

template<typename T, int WM>
__device__ void body(const T* obs, const T* eps_intra, const T* eps_inter,
                     const T* W_local, const T* b_local,
                     const T* W_inter, const T* b_inter,
                     const T* W_intra, const T* b_intra,
                     const T* Wqkv, const T* bqkv, const T* Wo, const T* bo,
                     const T* att_w, const T* att_b,
                     const T* W1, const T* b1, const T* W2, const T* b2,
                     const T* Wa, const T* ba, const T* Wv, const T* bv,
                     T* out_a, T* out_v, char* smem, const u16* wsw) {
    constexpr bool XSPLIT = (sizeof(T) == 4) && (WM == 1);  // obs hi/lo only in fallback
    const int tid = threadIdx.x;
    const size_t b0 = (size_t)blockIdx.x * 2;   // two consecutive batch rows per block
    const int wv = tid >> 6, lane = tid & 63, lo16 = lane & 15, hi = lane >> 4;

    const u16* wsh = wsw;
    const u16* wsl = (WM == 2) ? wsw + WS_TOTAL : nullptr;
#define WPAIR(OFF) ((WM == 2) ? wsh + (OFF) : nullptr), ((WM == 2) ? wsl + (OFF) : nullptr)

    u16* localb    = (u16*)(smem + L_LB);
    u16* iobs      = (u16*)(smem + L_IO);
    float* alog    = (float*)(smem + L_IO);
    u16* intra_e   = (u16*)(smem + L_IE);
    u16* nobs      = (u16*)(smem + L_IE);
    u16* hb        = (u16*)(smem + L_IE);
    u16* inter_e   = (u16*)(smem + L_NE);
    u16* qk        = (u16*)(smem + L_QK);
    u16* xh        = (u16*)(smem + L_QK);
    u16* vT        = (u16*)(smem + L_VT);
    u16* xl        = (u16*)(smem + L_VT);
    u16* atto      = (u16*)(smem + L_AT);
    u16* pooled_hi = (u16*)(smem + L_SC);          // [2][64]
    u16* pooled_lo = (u16*)(smem + L_SC + 256);    // [2][64]
    float* plog    = (float*)(smem + L_SC + 512);  // [2][32]
    float* pscore  = (float*)(smem + L_SC + 768);  // [2][32]

    // ---- P1a: stage obs (2 batches, contiguous 64x128) -> LDS bf16 ----
    {
        const T* ob = obs + b0 * (AA_ * OBSD);
#pragma unroll
        for (int it = 0; it < 2; it++) {
            const int i = tid + it * NT;        // 0..1023 groups of 8
            const int row = i >> 4, col = (i & 15) * 8;
            if constexpr (sizeof(T) == 4) {
                f32x4 f0 = __builtin_nontemporal_load((const f32x4*)(ob + i * 8));
                f32x4 f1 = __builtin_nontemporal_load((const f32x4*)(ob + i * 8) + 1);
                bf16x8 vh, vl;
#pragma unroll
                for (int j = 0; j < 8; j++) {
                    float fv = (j < 4) ? f0[j] : f1[j - 4];
                    u16 h = f2b(fv);
                    vh[j] = (short)h;
                    vl[j] = (short)f2b(fv - b2f(h));
                }
                *(bf16x8*)(xh + row * 136 + col) = vh;
                if constexpr (XSPLIT) *(bf16x8*)(xl + row * 136 + col) = vl;
            } else {
                bf16x8 v = __builtin_nontemporal_load((const bf16x8*)(ob + i * 8));
                *(bf16x8*)(xh + row * 136 + col) = v;
            }
        }
        // zero qk/xh pad columns 128..135 for all 64 rows (NaN guard, see r5 note)
        if (tid < 64) *(bf16x8*)(xh + tid * 136 + 128) = bzero8();
    }
    __syncthreads();

    // ---- P1b: local/intra/inter embeddings (24 units, each 16 cols x 64 rows) ----
#pragma unroll 1
    for (int u = wv; u < 24; u += 8) {
        const T *Wf, *bias; const u16 *Whi = nullptr, *Wlo = nullptr; u16* O; int ldo, nt;
        if (u < 16)      { Wf = W_local; bias = b_local; O = localb;  ldo = 264; nt = u;
                           if (WM == 2) { Whi = wsh + OFF_WLOCAL; Wlo = wsl + OFF_WLOCAL; } }
        else if (u < 20) { Wf = W_intra; bias = b_intra; O = intra_e; ldo = 72;  nt = u - 16;
                           if (WM == 2) { Whi = wsh + OFF_WINTRA; Wlo = wsl + OFF_WINTRA; } }
        else             { Wf = W_inter; bias = b_inter; O = inter_e; ldo = 72;  nt = u - 20;
                           if (WM == 2) { Whi = wsh + OFF_WINTER; Wlo = wsl + OFF_WINTER; } }
        f32x4 acc0 = {0.f,0.f,0.f,0.f}, acc1 = {0.f,0.f,0.f,0.f};
        f32x4 acc2 = {0.f,0.f,0.f,0.f}, acc3 = {0.f,0.f,0.f,0.f};
#pragma unroll
        for (int k0 = 0; k0 < OBSD; k0 += 32) {
            bf16x8 bh, bl;
            loadW<WM>(Wf, Whi, Wlo, OBSD, nt * 16 + lo16, k0 + hi * 8, bh, bl);
            bf16x8 a0 = *(const bf16x8*)(xh + lo16 * 136 + k0 + hi * 8);
            bf16x8 a1 = *(const bf16x8*)(xh + (16 + lo16) * 136 + k0 + hi * 8);
            bf16x8 a2 = *(const bf16x8*)(xh + (32 + lo16) * 136 + k0 + hi * 8);
            bf16x8 a3 = *(const bf16x8*)(xh + (48 + lo16) * 136 + k0 + hi * 8);
            acc0 = MFMA16(a0, bh, acc0);
            acc1 = MFMA16(a1, bh, acc1);
            acc2 = MFMA16(a2, bh, acc2);
            acc3 = MFMA16(a3, bh, acc3);
            if constexpr (WM == 1) {
                acc0 = MFMA16(a0, bl, acc0);
                acc1 = MFMA16(a1, bl, acc1);
                acc2 = MFMA16(a2, bl, acc2);
                acc3 = MFMA16(a3, bl, acc3);
            }
            if constexpr (XSPLIT) {
                bf16x8 l0 = *(const bf16x8*)(xl + lo16 * 136 + k0 + hi * 8);
                bf16x8 l1 = *(const bf16x8*)(xl + (16 + lo16) * 136 + k0 + hi * 8);
                bf16x8 l2 = *(const bf16x8*)(xl + (32 + lo16) * 136 + k0 + hi * 8);
                bf16x8 l3 = *(const bf16x8*)(xl + (48 + lo16) * 136 + k0 + hi * 8);
                acc0 = MFMA16(l0, bh, acc0);
                acc1 = MFMA16(l1, bh, acc1);
                acc2 = MFMA16(l2, bh, acc2);
                acc3 = MFMA16(l3, bh, acc3);
            }
        }
        float bb = tof(bias[nt * 16 + lo16]);
#pragma unroll
        for (int r = 0; r < 4; r++) {
            O[(hi * 4 + r) * ldo + nt * 16 + lo16] = f2b(fast_tanh(acc0[r] + bb));
            O[(16 + hi * 4 + r) * ldo + nt * 16 + lo16] = f2b(fast_tanh(acc1[r] + bb));
            O[(32 + hi * 4 + r) * ldo + nt * 16 + lo16] = f2b(fast_tanh(acc2[r] + bb));
            O[(48 + hi * 4 + r) * ldo + nt * 16 + lo16] = f2b(fast_tanh(acc3[r] + bb));
        }
    }
    __syncthreads();

    // ==== P2: 4 MHA nets (0:intra_mu 1:intra_std 2:inter_mu 3:inter_std) ====
#pragma unroll 1
    for (int net = 0; net < 4; net++) {
        qkv_pass<WM>(net, (net < 2) ? intra_e : inter_e, Wqkv, bqkv, wsh, wsl, qk, vT);
        __syncthreads();

        // fused scores + softmax + PV per batch; no LDS P-matrix.
        float epr[2][4] = {{0.f,0.f,0.f,0.f},{0.f,0.f,0.f,0.f}};
        {
            // prefetch eps for std-net outproj (consumed next phase)
            if (net == 1 || net == 3) {
                const T* epsb = ((net == 1) ? eps_intra : eps_inter) + b0 * (AA_ * MSGD);
                const int grp = wv >> 2, col = (wv & 3) * 16 + lo16;
#pragma unroll
                for (int s = 0; s < 2; s++)
#pragma unroll
                    for (int r = 0; r < 4; r++)
                        epr[s][r] = tof(__builtin_nontemporal_load(
                            epsb + (grp * 32 + s * 16 + hi * 4 + r) * MSGD + col));
            }
            const int h = wv >> 1, mt = wv & 1;
#pragma unroll 1
            for (int bt = 0; bt < 2; bt++) {
                const u16* qkB = qk + bt * 32 * 136;
                bf16x8 a0 = *(const bf16x8*)(qkB + lo16 * 136 + 64 + h * 16 + hi * 8);
                bf16x8 a1 = *(const bf16x8*)(qkB + (16 + lo16) * 136 + 64 + h * 16 + hi * 8);
                bf16x8 bq = bzero8();      // zero-pad dh 16->32 (B=0 kills k>=16 terms)
                if (hi < 2) bq = *(const bf16x8*)(qkB + (mt * 16 + lo16) * 136 + h * 16 + hi * 8);
                f32x4 z = {0.f, 0.f, 0.f, 0.f};
                f32x4 sc0 = MFMA16(a0, bq, z);
                f32x4 sc1 = MFMA16(a1, bq, z);
                float v0[4], v1[4];
#pragma unroll
                for (int r = 0; r < 4; r++) { v0[r] = sc0[r] * 0.25f; v1[r] = sc1[r] * 0.25f; }
                float m = fmaxf(fmaxf(fmaxf(v0[0], v0[1]), fmaxf(v0[2], v0[3])),
                                fmaxf(fmaxf(v1[0], v1[1]), fmaxf(v1[2], v1[3])));
                m = fmaxf(m, __shfl_xor(m, 16));
                m = fmaxf(m, __shfl_xor(m, 32));
                float e0[4], e1[4], s = 0.f;
#pragma unroll
                for (int r = 0; r < 4; r++) {
                    e0[r] = __expf(v0[r] - m); e1[r] = __expf(v1[r] - m);
                    s += e0[r] + e1[r];
                }
                s += __shfl_xor(s, 16);
                s += __shfl_xor(s, 32);
                float inv = __builtin_amdgcn_rcpf(s);
                u32 pk0 = (u32)f2b(e0[0] * inv) | ((u32)f2b(e0[1] * inv) << 16);
                u32 pk1 = (u32)f2b(e0[2] * inv) | ((u32)f2b(e0[3] * inv) << 16);
                u32 pk2 = (u32)f2b(e1[0] * inv) | ((u32)f2b(e1[1] * inv) << 16);
                u32 pk3 = (u32)f2b(e1[2] * inv) | ((u32)f2b(e1[3] * inv) << 16);
                const int sA = (((hi * 2) & 3) << 4) | lo16;
                const int sB = sA + 16;
                u32 wA0 = __shfl(pk0, sA), wA1 = __shfl(pk1, sA);
                u32 wB0 = __shfl(pk0, sB), wB1 = __shfl(pk1, sB);
                u32 xA0 = __shfl(pk2, sA), xA1 = __shfl(pk3, sA);
                u32 xB0 = __shfl(pk2, sB), xB1 = __shfl(pk3, sB);
                const bool lo = (hi < 2);
                union { u32 w[4]; bf16x8 v; } pu;
                pu.w[0] = lo ? wA0 : xA0;
                pu.w[1] = lo ? wA1 : xA1;
                pu.w[2] = lo ? wB0 : xB0;
                pu.w[3] = lo ? wB1 : xB1;
                bf16x8 bv_ = *(const bf16x8*)(vT + bt * 2560 + (h * 16 + lo16) * 40 + hi * 8);
                f32x4 o = MFMA16(pu.v, bv_, z);
#pragma unroll
                for (int r = 0; r < 4; r++)
                    atto[(bt * 32 + mt * 16 + hi * 4 + r) * 72 + h * 16 + lo16] = f2b(o[r]);
            }
        }
        __syncthreads();

        // out projection: wave -> (ntU = n-tile, grp = batch). mu raw, std softplus*eps.
        {
            const T* Won = Wo + (size_t)net * MSGD * MSGD;
            const T* bon = bo + (size_t)net * MSGD;
            const u16* Ohi = (WM == 2) ? wsh + OFF_WO + net * 4096 : nullptr;
            const u16* Olo = (WM == 2) ? wsl + OFF_WO + net * 4096 : nullptr;
            const int ntU = wv & 3, grp = wv >> 2, col = ntU * 16 + lo16;
            f32x4 acc0 = {0.f,0.f,0.f,0.f}, acc1 = {0.f,0.f,0.f,0.f};
#pragma unroll
            for (int k0 = 0; k0 < 64; k0 += 32) {
                bf16x8 bh, bl;
                loadW<WM>(Won, Ohi, Olo, 64, col, k0 + hi * 8, bh, bl);
                bf16x8 aA = *(const bf16x8*)(atto + (grp * 32 + lo16) * 72 + k0 + hi * 8);
                bf16x8 aB = *(const bf16x8*)(atto + (grp * 32 + 16 + lo16) * 72 + k0 + hi * 8);
                acc0 = MFMA16(aA, bh, acc0);
                acc1 = MFMA16(aB, bh, acc1);
                if constexpr (WM == 1) {
                    acc0 = MFMA16(aA, bl, acc0);
                    acc1 = MFMA16(aB, bl, acc1);
                }
            }
            float bb = tof(bon[col]);
            u16* tgt = (net < 2) ? iobs : nobs;
#pragma unroll
            for (int s = 0; s < 2; s++) {
                f32x4 acc = s ? acc1 : acc0;
#pragma unroll
                for (int r = 0; r < 4; r++) {
                    const int row = grp * 32 + s * 16 + hi * 4 + r;
                    if (net == 0 || net == 2) {
                        tgt[row * 72 + col] = f2b(acc[r] + bb);
                    } else {
                        float zv = acc[r] + bb - 5.f;
                        float sp = (zv > 20.f) ? zv : __logf(1.f + __expf(zv));
                        tgt[row * 72 + col] = f2b(b2f(tgt[row * 72 + col]) + sp * epr[s][r]);
                    }
                }
            }
        }
        __syncthreads();
    }

    // ---- P3: attention pooling, one wave per batch (wave-synchronous) ----
    if (wv < 2) {
        const int bt = wv;
        if (lane < 32) {
            float acc = tof(att_b[0]);
            const u16* xr = nobs + (bt * 32 + lane) * 72;
#pragma unroll
            for (int j = 0; j < 64; j += 8) {
                bf16x8 x = *(const bf16x8*)(xr + j);
#pragma unroll
                for (int jj = 0; jj < 8; jj++) acc = fmaf(b2f((u16)x[jj]), tof(att_w[j + jj]), acc);
            }
            plog[bt * 32 + lane] = acc;
        }
        __builtin_amdgcn_wave_barrier();
        if (lane < 32) {
            float m = -1e30f;
            for (int a2 = 0; a2 < 32; a2++) m = fmaxf(m, plog[bt * 32 + a2]);
            float s = 0.f;
            for (int a2 = 0; a2 < 32; a2++) s += __expf(plog[bt * 32 + a2] - m);
            pscore[bt * 32 + lane] = __expf(plog[bt * 32 + lane] - m) * __builtin_amdgcn_rcpf(s);
        }
        __builtin_amdgcn_wave_barrier();
        {
            float p = 0.f;
            for (int a2 = 0; a2 < 32; a2++)
                p = fmaf(pscore[bt * 32 + a2], b2f(nobs[(bt * 32 + a2) * 72 + lane]), p);
            u16 h = f2b(p);
            pooled_hi[bt * 64 + lane] = h;
            pooled_lo[bt * 64 + lane] = f2b(p - b2f(h));
        }
    }
    __syncthreads();

    // ---- P4: h = tanh([local | intra_obs | pooled] @ W1^T + b1), M=64 ----
#pragma unroll 1
    for (int nt = wv; nt < 16; nt += 8) {
        const int n = nt * 16 + lo16;
        f32x4 acc0 = {0.f,0.f,0.f,0.f}, acc1 = {0.f,0.f,0.f,0.f};
        f32x4 acc2 = {0.f,0.f,0.f,0.f}, acc3 = {0.f,0.f,0.f,0.f};
        f32x4 accp0 = {0.f,0.f,0.f,0.f}, accp1 = {0.f,0.f,0.f,0.f};
#pragma unroll
        for (int k0 = 0; k0 < 256; k0 += 32) {
            bf16x8 bh, bl;
            loadW<WM>(W1, WPAIR(OFF_W1), 384, n, k0 + hi * 8, bh, bl);
            bf16x8 a0 = *(const bf16x8*)(localb + lo16 * 264 + k0 + hi * 8);
            bf16x8 a1 = *(const bf16x8*)(localb + (16 + lo16) * 264 + k0 + hi * 8);
            bf16x8 a2 = *(const bf16x8*)(localb + (32 + lo16) * 264 + k0 + hi * 8);
            bf16x8 a3 = *(const bf16x8*)(localb + (48 + lo16) * 264 + k0 + hi * 8);
            acc0 = MFMA16(a0, bh, acc0);
            acc1 = MFMA16(a1, bh, acc1);
            acc2 = MFMA16(a2, bh, acc2);
            acc3 = MFMA16(a3, bh, acc3);
            if constexpr (WM == 1) {
                acc0 = MFMA16(a0, bl, acc0); acc1 = MFMA16(a1, bl, acc1);
                acc2 = MFMA16(a2, bl, acc2); acc3 = MFMA16(a3, bl, acc3);
            }
        }
#pragma unroll
        for (int k0 = 0; k0 < 64; k0 += 32) {
            bf16x8 bh, bl;
            loadW<WM>(W1, WPAIR(OFF_W1), 384, n, 256 + k0 + hi * 8, bh, bl);
            bf16x8 a0 = *(const bf16x8*)(iobs + lo16 * 72 + k0 + hi * 8);
            bf16x8 a1 = *(const bf16x8*)(iobs + (16 + lo16) * 72 + k0 + hi * 8);
            bf16x8 a2 = *(const bf16x8*)(iobs + (32 + lo16) * 72 + k0 + hi * 8);
            bf16x8 a3 = *(const bf16x8*)(iobs + (48 + lo16) * 72 + k0 + hi * 8);
            acc0 = MFMA16(a0, bh, acc0);
            acc1 = MFMA16(a1, bh, acc1);
            acc2 = MFMA16(a2, bh, acc2);
            acc3 = MFMA16(a3, bh, acc3);
            if constexpr (WM == 1) {
                acc0 = MFMA16(a0, bl, acc0); acc1 = MFMA16(a1, bl, acc1);
                acc2 = MFMA16(a2, bl, acc2); acc3 = MFMA16(a3, bl, acc3);
            }
        }
        // pooled segment: per-batch broadcast MFMA (pooled hi/lo kept: in-LDS, no loads)
#pragma unroll
        for (int k0 = 0; k0 < 64; k0 += 32) {
            bf16x8 bh, bl;
            loadW<WM>(W1, WPAIR(OFF_W1), 384, n, 320 + k0 + hi * 8, bh, bl);
            bf16x8 pa0  = *(const bf16x8*)(pooled_hi + k0 + hi * 8);
            bf16x8 pal0 = *(const bf16x8*)(pooled_lo + k0 + hi * 8);
            bf16x8 pa1  = *(const bf16x8*)(pooled_hi + 64 + k0 + hi * 8);
            bf16x8 pal1 = *(const bf16x8*)(pooled_lo + 64 + k0 + hi * 8);
            accp0 = MFMA16(pa0, bh, accp0);
            accp0 = MFMA16(pal0, bh, accp0);
            accp1 = MFMA16(pa1, bh, accp1);
            accp1 = MFMA16(pal1, bh, accp1);
            if constexpr (WM == 1) {
                accp0 = MFMA16(pa0, bl, accp0);
                accp1 = MFMA16(pa1, bl, accp1);
            }
        }
        float bb0 = tof(b1[n]) + accp0[0];
        float bb1 = tof(b1[n]) + accp1[0];
#pragma unroll
        for (int r = 0; r < 4; r++) {
            hb[(hi * 4 + r) * 264 + n] = f2b(fast_tanh(acc0[r] + bb0));
            hb[(16 + hi * 4 + r) * 264 + n] = f2b(fast_tanh(acc1[r] + bb0));
            hb[(32 + hi * 4 + r) * 264 + n] = f2b(fast_tanh(acc2[r] + bb1));
            hb[(48 + hi * 4 + r) * 264 + n] = f2b(fast_tanh(acc3[r] + bb1));
        }
    }
    __syncthreads();

    // ---- P5: h2 = tanh(h @ W2^T + b2)  (h2 overlays localb; local is dead) ----
    mdense64<256, 256, 1, WM>(hb, 264, W2, WPAIR(OFF_W2), b2, localb, 264);
    __syncthreads();

    // ---- P6: heads ----
    if constexpr (WM == 2) {
        // augmented head [32][256]: rows 0-15 Wa, 16 Wv, 17-31 zero. 8 units = 8 waves.
        const int ntU = wv & 1, rg = wv >> 1;   // rg: 16-row group of h2 (0..3)
        const u16* Hhi = wsh + OFF_WHEAD;
        f32x4 acc = {0.f, 0.f, 0.f, 0.f};
#pragma unroll
        for (int k0 = 0; k0 < 256; k0 += 32) {
            bf16x8 bh = *(const bf16x8*)(Hhi + (size_t)(ntU * 16 + lo16) * 256 + k0 + hi * 8);
            bf16x8 a = *(const bf16x8*)(localb + (rg * 16 + lo16) * 264 + k0 + hi * 8);
            acc = MFMA16(a, bh, acc);
        }
#pragma unroll
        for (int r = 0; r < 4; r++) {
            const int row = rg * 16 + hi * 4 + r;
            if (ntU == 0) alog[row * 18 + lo16] = acc[r] + tof(ba[lo16]);
            else if (lo16 == 0) out_v[b0 * 32 + row] = fromf<T>(acc[r] + tof(bv[0]));
        }
    } else {
        if (wv < 2) {           // Wa logits, 32 rows per wave
            f32x4 acc0 = {0.f,0.f,0.f,0.f}, acc1 = {0.f,0.f,0.f,0.f};
#pragma unroll
            for (int k0 = 0; k0 < 256; k0 += 32) {
                bf16x8 bh, bl;
                loadW<WM>(Wa, nullptr, nullptr, 256, lo16, k0 + hi * 8, bh, bl);
                bf16x8 a0 = *(const bf16x8*)(localb + (wv * 32 + lo16) * 264 + k0 + hi * 8);
                bf16x8 a1 = *(const bf16x8*)(localb + (wv * 32 + 16 + lo16) * 264 + k0 + hi * 8);
                acc0 = MFMA16(a0, bh, acc0);
                acc1 = MFMA16(a1, bh, acc1);
                if constexpr (WM == 1) { acc0 = MFMA16(a0, bl, acc0); acc1 = MFMA16(a1, bl, acc1); }
            }
            float bb = tof(ba[lo16]);
#pragma unroll
            for (int r = 0; r < 4; r++) {
                alog[(wv * 32 + hi * 4 + r) * 18 + lo16] = acc0[r] + bb;
                alog[(wv * 32 + 16 + hi * 4 + r) * 18 + lo16] = acc1[r] + bb;
            }
        } else if (wv < 4 && lane < 32) {   // value head rows (wv-2)*32+lane
            const int row = (wv - 2) * 32 + lane;
            const u16* xr = localb + row * 264;
            float acc = tof(bv[0]);
            for (int k0 = 0; k0 < 256; k0 += 8) {
                bf16x8 x = *(const bf16x8*)(xr + k0);
#pragma unroll
                for (int j = 0; j < 8; j++) acc = fmaf(b2f((u16)x[j]), tof(Wv[k0 + j]), acc);
            }
            out_v[b0 * 32 + row] = fromf<T>(acc);
        }
    }
    __syncthreads();
    if (tid < 64) {         // log-softmax + packed store, 64 rows
        const float* lr = alog + tid * 18;
        float m = -1e30f;
#pragma unroll
        for (int n = 0; n < 16; n++) m = fmaxf(m, lr[n]);
        float s = 0.f;
#pragma unroll
        for (int n = 0; n < 16; n++) s += __expf(lr[n] - m);
        float lse = m + __logf(s);
        if constexpr (sizeof(T) == 2) {
            bf16x8 o0, o1;
#pragma unroll
            for (int n = 0; n < 8; n++) {
                o0[n] = (short)f2b(lr[n] - lse);
                o1[n] = (short)f2b(lr[8 + n] - lse);
            }
            bf16x8* oa = (bf16x8*)((u16*)out_a + (b0 * 32 + tid) * 16);
            oa[0] = o0; oa[1] = o1;
        } else {
            float* oa = (float*)out_a + (b0 * 32 + tid) * 16;
#pragma unroll
            for (int g = 0; g < 4; g++) {
                f32x4 t = {lr[4 * g] - lse, lr[4 * g + 1] - lse,
                           lr[4 * g + 2] - lse, lr[4 * g + 3] - lse};
                *(f32x4*)(oa + 4 * g) = t;
            }
        }
    }
#undef WPAIR
}

// dtype detect: fp32 misread as bf16 has uniform-random low halfwords -> some
// exponent field >= 0x90 among the first 64 halfwords w.p. ~1-1e-8.
__device__ __forceinline__ int detect_f32(const void* obs) {
    const unsigned short* u = (const unsigned short*)obs;
    int e = ((int)u[threadIdx.x & 63] >> 7) & 0xFF;
    return __ballot(e >= 0x90) != 0ull;
}

// prep: split all MFMA weights f32 -> bf16 hi/lo into workspace (f32 inputs only).
extern "C" __global__ void TeamCommAgent_prep_kernel(
    const void* obs, const void* Wl, const void* Wi, const void* Wt,
    const void* Wq, const void* Wo_, const void* W1_, const void* W2_,
    const void* Wa_, const void* Wv_, u16* ws) {
    if (!detect_f32(obs)) return;
    int i = blockIdx.x * blockDim.x + threadIdx.x;
    if (i >= WS_TOTAL) return;
    float w;
    if (i >= OFF_WHEAD) {
        int local = i - OFF_WHEAD, row = local >> 8, col = local & 255;
        w = (row < 16) ? ((const float*)Wa_)[row * 256 + col]
          : (row == 16) ? ((const float*)Wv_)[col] : 0.f;
    } else {
        const float* src; int off;
        if (i < OFF_WINTER)      { src = (const float*)Wl;  off = OFF_WLOCAL; }
        else if (i < OFF_WINTRA) { src = (const float*)Wi;  off = OFF_WINTER; }
        else if (i < OFF_WQKV)   { src = (const float*)Wt;  off = OFF_WINTRA; }
        else if (i < OFF_WO)     { src = (const float*)Wq;  off = OFF_WQKV; }
        else if (i < OFF_W1)     { src = (const float*)Wo_; off = OFF_WO; }
        else if (i < OFF_W2)     { src = (const float*)W1_; off = OFF_W1; }
        else if (i < OFF_WA)     { src = (const float*)W2_; off = OFF_W2; }
        else                     { src = (const float*)Wa_; off = OFF_WA; }
        w = src[i - off];
    }
    u16 h = f2b(w);
    ws[i] = h;
    ws[WS_TOTAL + i] = f2b(w - b2f(h));
}

extern "C" __global__ void __launch_bounds__(NT, 2)
TeamCommAgent_53077205844655_kernel(
    const void* obs, const void* eps_intra, const void* eps_inter,
    const void* W_local, const void* b_local,
    const void* W_inter, const void* b_inter,
    const void* W_intra, const void* b_intra,
    const void* Wqkv, const void* bqkv, const void* Wo, const void* bo,
    const void* att_w, const void* att_b,
    const void* W1, const void* b1, const void* W2, const void* b2,
    const void* Wa, const void* ba, const void* Wv, const void* bv,
    void* out, const u16* wsw) {
    __shared__ __align__(16) char smem[SMEM_SZ];
    if (detect_f32(obs)) {
        if (wsw) {
            body<float, 2>((const float*)obs, (const float*)eps_intra, (const float*)eps_inter,
                           (const float*)W_local, (const float*)b_local,
                           (const float*)W_inter, (const float*)b_inter,
                           (const float*)W_intra, (const float*)b_intra,
                           (const float*)Wqkv, (const float*)bqkv,
                           (const float*)Wo, (const float*)bo,
                           (const float*)att_w, (const float*)att_b,
                           (const float*)W1, (const float*)b1,
                           (const float*)W2, (const float*)b2,
                           (const float*)Wa, (const float*)ba,
                           (const float*)Wv, (const float*)bv,
                           (float*)out, (float*)out + (size_t)BB * AA_ * NACTD, smem, wsw);
        } else {
            body<float, 1>((const float*)obs, (const float*)eps_intra, (const float*)eps_inter,
                           (const float*)W_local, (const float*)b_local,
                           (const float*)W_inter, (const float*)b_inter,
                           (const float*)W_intra, (const float*)b_intra,
                           (const float*)Wqkv, (const float*)bqkv,
                           (const float*)Wo, (const float*)bo,
                           (const float*)att_w, (const float*)att_b,
                           (const float*)W1, (const float*)b1,
                           (const float*)W2, (const float*)b2,
                           (const float*)Wa, (const float*)ba,
                           (const float*)Wv, (const float*)bv,
                           (float*)out, (float*)out + (size_t)BB * AA_ * NACTD, smem, nullptr);
        }
    } else {
        body<u16, 0>((const u16*)obs, (const u16*)eps_intra, (const u16*)eps_inter,
                     (const u16*)W_local, (const u16*)b_local,
                     (const u16*)W_inter, (const u16*)b_inter,
                     (const u16*)W_intra, (const u16*)b_intra,
                     (const u16*)Wqkv, (const u16*)bqkv,
                     (const u16*)Wo, (const u16*)bo,
                     (const u16*)att_w, (const u16*)att_b,
                     (const u16*)W1, (const u16*)b1,
                     (const u16*)W2, (const u16*)b2,
                     (const u16*)Wa, (const u16*)ba,
                     (const u16*)Wv, (const u16*)bv,
                     (u16*)out, (u16*)out + (size_t)BB * AA_ * NACTD, smem, nullptr);
    }
}

extern "C" void kernel_launch(void* const* d_in, const int* in_sizes, int n_in,
                              void* d_out, int out_size, void* d_ws, size_t ws_size,
                              hipStream_t stream) {
    const bool use_ws = (d_ws != nullptr) &&
                        (ws_size >= (size_t)(2 * WS_TOTAL) * sizeof(u16));
    if (use_ws) {
        TeamCommAgent_prep_kernel<<<dim3((WS_TOTAL + 255) / 256), dim3(256), 0, stream>>>(
            d_in[0], d_in[3], d_in[5], d_in[7], d_in[9], d_in[11],
            d_in[15], d_in[17], d_in[19], d_in[21], (u16*)d_ws);
    }
    TeamCommAgent_53077205844655_kernel<<<dim3(BB / 2), dim3(NT), 0, stream>>>(
        d_in[0], d_in[1], d_in[2], d_in[3], d_in[4], d_in[5], d_in[6],
        d_in[7], d_in[8], d_in[9], d_in[10], d_in[11], d_in[12], d_in[13],
        d_in[14], d_in[15], d_in[16], d_in[17], d_in[18], d_in[19], d_in[20],
        d_in[21], d_in[22], d_out, use_ws ? (const u16*)d_ws : nullptr);
}

// Round 11
// 462.843 us; speedup vs baseline: 1.0389x; 1.0389x over previous
//
#include <hip/hip_runtime.h>

#define BB 4096
#define AA_ 32
#define OBSD 128
#define HIDD 256
#define MSGD 64
#define NHH 4
#define DHH 16
#define NACTD 16
#define NT 512

// workspace pre-split weight layout (element offsets; hi at [i], lo at [WS_TOTAL+i])
// WM=2 reads ONLY hi (bf16 weights); lo kept for WM=1-compat layout.
#define OFF_WLOCAL 0
#define OFF_WINTER 32768
#define OFF_WINTRA 40960
#define OFF_WQKV   49152
#define OFF_WO     98304
#define OFF_W1     114688
#define OFF_W2     212992
#define OFF_WA     278528
#define OFF_WHEAD  282624   // augmented head [32][256]: rows 0-15 Wa, 16 Wv, 17-31 zero
#define WS_TOTAL   290816

// LDS arena (bytes), total 99328 -> 1 block/CU. M=64: rows 0-31 batch b0, 32-63 b0+1.
//  L_LB 0      localb [64][264] 33792  (h2 in P5->P6)
//  L_IO 33792  iobs [64][72] 9216      (alog [64][18]f32 in P6)
//  L_IE 43008  intra_e [64][72]        (nobs net2/3 | hb [64][264] P4->P5)
//  L_NE 52224  inter_e [64][72]
//  L_QK 61440  qk [64][136] (q 0-63, k 64-127, 128-135 ZEROED pad) | xh (P1)
//  L_VT 78848  vT [2][64][40] 10240    (xl [64][136] in P1, WM=1 only)
//  L_AT 89088  atto [64][72] 9216
//  L_SC 98304  pooled_hi[128]u16, pooled_lo[128]u16, plog[64]f32, pscore[64]f32
#define L_LB 0
#define L_IO 33792
#define L_IE 43008
#define L_NE 52224
#define L_QK 61440
#define L_VT 78848
#define L_AT 89088
#define L_SC 98304
#define SMEM_SZ 99328

typedef unsigned short u16;
typedef unsigned int u32;
typedef __attribute__((ext_vector_type(8))) short bf16x8;
typedef __attribute__((ext_vector_type(4))) float f32x4;

#define MFMA16(a, b, c) __builtin_amdgcn_mfma_f32_16x16x32_bf16((a), (b), (c), 0, 0, 0)

__device__ __forceinline__ float b2f(u16 s) { return __uint_as_float((u32)s << 16); }
__device__ __forceinline__ u16 f2b(float f) {
    u32 u = __float_as_uint(f);
    u += 0x7FFFu + ((u >> 16) & 1u);   // round-to-nearest-even
    return (u16)(u >> 16);
}
__device__ __forceinline__ float tof(float x) { return x; }
__device__ __forceinline__ float tof(u16 x) { return b2f(x); }
template<typename T> __device__ __forceinline__ T fromf(float v);
template<> __device__ __forceinline__ float fromf<float>(float v) { return v; }
template<> __device__ __forceinline__ u16 fromf<u16>(float v) { return f2b(v); }

__device__ __forceinline__ bf16x8 bzero8() { bf16x8 v = {0,0,0,0,0,0,0,0}; return v; }
__device__ __forceinline__ f32x4 fzero4() { f32x4 v = {0.f,0.f,0.f,0.f}; return v; }

// fast tanh: err ~1e-6, far below bf16 storage quantum
__device__ __forceinline__ float fast_tanh(float x) {
    float ax = fabsf(x);
    float e = __expf(-2.f * ax);
    float t = (1.f - e) * __builtin_amdgcn_rcpf(1.f + e);
    return copysignf(t, x);
}

// Weight fragment loader. WM: 0 = bf16 direct (T=u16), 1 = f32 self-split (T=float,
// hi/lo 2-MFMA path), 2 = pre-split bf16 hi ONLY from workspace (1 MFMA).
template<int WM, typename T>
__device__ __forceinline__ void loadW(const T* Wf, const u16* Whi, const u16* Wlo,
                                      int ldw, int n, int k, bf16x8& bh, bf16x8& bl) {
    if constexpr (WM == 0) {
        bh = *(const bf16x8*)((const u16*)Wf + (size_t)n * ldw + k);
    } else if constexpr (WM == 2) {
        bh = *(const bf16x8*)(Whi + (size_t)n * ldw + k);
        (void)Wlo;
    } else {
        const float* p = (const float*)Wf + (size_t)n * ldw + k;
        f32x4 f0 = *(const f32x4*)(p);
        f32x4 f1 = *(const f32x4*)(p + 4);
#pragma unroll
        for (int j = 0; j < 8; j++) {
            float fv = (j < 4) ? f0[j] : f1[j - 4];
            u16 h = f2b(fv);
            bh[j] = (short)h;
            bl[j] = (short)f2b(fv - b2f(h));
        }
    }
}

// O[0..63][0..N) = act(X[64xK] @ W^T + bias); 4 row-tiles per weight fragment.
// K-PARITY SPLIT: even/odd k-steps accumulate into independent accs (halves the
// serial MFMA dependency chain; summed once at the end).
template<int N, int K, int ACT, int WM, typename T>
__device__ __forceinline__ void mdense64(const u16* X, int ldx,
                                         const T* Wf, const u16* Whi, const u16* Wlo,
                                         const T* bias, u16* O, int ldo) {
    const int tid = threadIdx.x;
    const int wv = tid >> 6, lo16 = tid & 15, hi = (tid & 63) >> 4;
    for (int nt = wv; nt < N / 16; nt += 8) {
        f32x4 acc[2][4];
#pragma unroll
        for (int p = 0; p < 2; p++)
#pragma unroll
            for (int i = 0; i < 4; i++) acc[p][i] = fzero4();
#pragma unroll
        for (int k0 = 0; k0 < K; k0 += 32) {
            const int p = (k0 >> 5) & 1;
            bf16x8 bh, bl;
            loadW<WM>(Wf, Whi, Wlo, K, nt * 16 + lo16, k0 + hi * 8, bh, bl);
            bf16x8 a0 = *(const bf16x8*)(X + lo16 * ldx + k0 + hi * 8);
            bf16x8 a1 = *(const bf16x8*)(X + (16 + lo16) * ldx + k0 + hi * 8);
            bf16x8 a2 = *(const bf16x8*)(X + (32 + lo16) * ldx + k0 + hi * 8);
            bf16x8 a3 = *(const bf16x8*)(X + (48 + lo16) * ldx + k0 + hi * 8);
            acc[p][0] = MFMA16(a0, bh, acc[p][0]);
            acc[p][1] = MFMA16(a1, bh, acc[p][1]);
            acc[p][2] = MFMA16(a2, bh, acc[p][2]);
            acc[p][3] = MFMA16(a3, bh, acc[p][3]);
            if constexpr (WM == 1) {
                acc[p][0] = MFMA16(a0, bl, acc[p][0]);
                acc[p][1] = MFMA16(a1, bl, acc[p][1]);
                acc[p][2] = MFMA16(a2, bl, acc[p][2]);
                acc[p][3] = MFMA16(a3, bl, acc[p][3]);
            }
        }
        float bb = tof(bias[nt * 16 + lo16]);
#pragma unroll
        for (int i = 0; i < 4; i++) {
            f32x4 fin = acc[0][i] + acc[1][i];
#pragma unroll
            for (int r = 0; r < 4; r++) {
                float v = fin[r] + bb;
                if (ACT) v = fast_tanh(v);
                O[(i * 16 + hi * 4 + r) * ldo + nt * 16 + lo16] = f2b(v);
            }
        }
    }
}

// QKV pass for one net (M=64): q,k -> qk[row][col]; v -> per-batch transposed vT.
// K=64 (2 k-steps) -> parity split gives chain length 1 per acc.
template<int WM, typename T>
__device__ __forceinline__ void qkv_pass(int net, const u16* xe,
                                         const T* Wqkv, const T* bqkv,
                                         const u16* wsh, const u16* wsl,
                                         u16* qk, u16* vT) {
    const int tid = threadIdx.x;
    const int wv = tid >> 6, lo16 = tid & 15, hi = (tid & 63) >> 4;
    const T* Wq = Wqkv + (size_t)net * 192 * MSGD;
    const T* bq_ = bqkv + (size_t)net * 192;
    const u16* Whi = (WM == 2) ? wsh + OFF_WQKV + net * 192 * MSGD : nullptr;
    const u16* Wlo = (WM == 2) ? wsl + OFF_WQKV + net * 192 * MSGD : nullptr;
    for (int nt = wv; nt < 12; nt += 8) {
        f32x4 acc[2][4];
#pragma unroll
        for (int p = 0; p < 2; p++)
#pragma unroll
            for (int i = 0; i < 4; i++) acc[p][i] = fzero4();
#pragma unroll
        for (int k0 = 0; k0 < 64; k0 += 32) {
            const int p = (k0 >> 5) & 1;
            bf16x8 bh, bl;
            loadW<WM>(Wq, Whi, Wlo, 64, nt * 16 + lo16, k0 + hi * 8, bh, bl);
            bf16x8 a0 = *(const bf16x8*)(xe + lo16 * 72 + k0 + hi * 8);
            bf16x8 a1 = *(const bf16x8*)(xe + (16 + lo16) * 72 + k0 + hi * 8);
            bf16x8 a2 = *(const bf16x8*)(xe + (32 + lo16) * 72 + k0 + hi * 8);
            bf16x8 a3 = *(const bf16x8*)(xe + (48 + lo16) * 72 + k0 + hi * 8);
            acc[p][0] = MFMA16(a0, bh, acc[p][0]);
            acc[p][1] = MFMA16(a1, bh, acc[p][1]);
            acc[p][2] = MFMA16(a2, bh, acc[p][2]);
            acc[p][3] = MFMA16(a3, bh, acc[p][3]);
            if constexpr (WM == 1) {
                acc[p][0] = MFMA16(a0, bl, acc[p][0]);
                acc[p][1] = MFMA16(a1, bl, acc[p][1]);
                acc[p][2] = MFMA16(a2, bl, acc[p][2]);
                acc[p][3] = MFMA16(a3, bl, acc[p][3]);
            }
        }
        f32x4 f0 = acc[0][0] + acc[1][0];
        f32x4 f1 = acc[0][1] + acc[1][1];
        f32x4 f2 = acc[0][2] + acc[1][2];
        f32x4 f3 = acc[0][3] + acc[1][3];
        float bb = tof(bq_[nt * 16 + lo16]);
        if (nt < 8) {
#pragma unroll
            for (int r = 0; r < 4; r++) {
                qk[(hi * 4 + r) * 136 + nt * 16 + lo16] = f2b(f0[r] + bb);
                qk[(16 + hi * 4 + r) * 136 + nt * 16 + lo16] = f2b(f1[r] + bb);
                qk[(32 + hi * 4 + r) * 136 + nt * 16 + lo16] = f2b(f2[r] + bb);
                qk[(48 + hi * 4 + r) * 136 + nt * 16 + lo16] = f2b(f3[r] + bb);
            }
        } else {
            const int d = (nt - 8) * 16 + lo16;
#pragma unroll
            for (int r = 0; r < 4; r++) {
                vT[d * 40 + hi * 4 + r] = f2b(f0[r] + bb);               // batch0
                vT[d * 40 + 16 + hi * 4 + r] = f2b(f1[r] + bb);
                vT[2560 + d * 40 + hi * 4 + r] = f2b(f2[r] + bb);        // batch1
                vT[2560 + d * 40 + 16 + hi * 4 + r] = f2b(f3[r] + bb);
            }
        }
    }
}

template<typename T, int WM>
__device__ void body(const T* obs, const T* eps_intra, const T* eps_inter,
                     const T* W_local, const T* b_local,
                     const T* W_inter, const T* b_inter,
                     const T* W_intra, const T* b_intra,
                     const T* Wqkv, const T* bqkv, const T* Wo, const T* bo,
                     const T* att_w, const T* att_b,
                     const T* W1, const T* b1, const T* W2, const T* b2,
                     const T* Wa, const T* ba, const T* Wv, const T* bv,
                     T* out_a, T* out_v, char* smem, const u16* wsw) {
    constexpr bool XSPLIT = (sizeof(T) == 4) && (WM == 1);  // obs hi/lo only in fallback
    const int tid = threadIdx.x;
    const size_t b0 = (size_t)blockIdx.x * 2;   // two consecutive batch rows per block
    const int wv = tid >> 6, lane = tid & 63, lo16 = lane & 15, hi = lane >> 4;

    const u16* wsh = wsw;
    const u16* wsl = (WM == 2) ? wsw + WS_TOTAL : nullptr;
#define WPAIR(OFF) ((WM == 2) ? wsh + (OFF) : nullptr), ((WM == 2) ? wsl + (OFF) : nullptr)

    u16* localb    = (u16*)(smem + L_LB);
    u16* iobs      = (u16*)(smem + L_IO);
    float* alog    = (float*)(smem + L_IO);
    u16* intra_e   = (u16*)(smem + L_IE);
    u16* nobs      = (u16*)(smem + L_IE);
    u16* hb        = (u16*)(smem + L_IE);
    u16* inter_e   = (u16*)(smem + L_NE);
    u16* qk        = (u16*)(smem + L_QK);
    u16* xh        = (u16*)(smem + L_QK);
    u16* vT        = (u16*)(smem + L_VT);
    u16* xl        = (u16*)(smem + L_VT);
    u16* atto      = (u16*)(smem + L_AT);
    u16* pooled_hi = (u16*)(smem + L_SC);          // [2][64]
    u16* pooled_lo = (u16*)(smem + L_SC + 256);    // [2][64]
    float* plog    = (float*)(smem + L_SC + 512);  // [2][32]
    float* pscore  = (float*)(smem + L_SC + 768);  // [2][32]

    // ---- P1a: stage obs (2 batches, contiguous 64x128) -> LDS bf16 ----
    {
        const T* ob = obs + b0 * (AA_ * OBSD);
#pragma unroll
        for (int it = 0; it < 2; it++) {
            const int i = tid + it * NT;        // 0..1023 groups of 8
            const int row = i >> 4, col = (i & 15) * 8;
            if constexpr (sizeof(T) == 4) {
                f32x4 f0 = __builtin_nontemporal_load((const f32x4*)(ob + i * 8));
                f32x4 f1 = __builtin_nontemporal_load((const f32x4*)(ob + i * 8) + 1);
                bf16x8 vh, vl;
#pragma unroll
                for (int j = 0; j < 8; j++) {
                    float fv = (j < 4) ? f0[j] : f1[j - 4];
                    u16 h = f2b(fv);
                    vh[j] = (short)h;
                    vl[j] = (short)f2b(fv - b2f(h));
                }
                *(bf16x8*)(xh + row * 136 + col) = vh;
                if constexpr (XSPLIT) *(bf16x8*)(xl + row * 136 + col) = vl;
            } else {
                bf16x8 v = __builtin_nontemporal_load((const bf16x8*)(ob + i * 8));
                *(bf16x8*)(xh + row * 136 + col) = v;
            }
        }
        // zero qk/xh pad columns 128..135 for all 64 rows (NaN guard, see r5 note)
        if (tid < 64) *(bf16x8*)(xh + tid * 136 + 128) = bzero8();
    }
    __syncthreads();

    // ---- P1b: local/intra/inter embeddings (24 units, each 16 cols x 64 rows) ----
#pragma unroll 1
    for (int u = wv; u < 24; u += 8) {
        const T *Wf, *bias; const u16 *Whi = nullptr, *Wlo = nullptr; u16* O; int ldo, nt;
        if (u < 16)      { Wf = W_local; bias = b_local; O = localb;  ldo = 264; nt = u;
                           if (WM == 2) { Whi = wsh + OFF_WLOCAL; Wlo = wsl + OFF_WLOCAL; } }
        else if (u < 20) { Wf = W_intra; bias = b_intra; O = intra_e; ldo = 72;  nt = u - 16;
                           if (WM == 2) { Whi = wsh + OFF_WINTRA; Wlo = wsl + OFF_WINTRA; } }
        else             { Wf = W_inter; bias = b_inter; O = inter_e; ldo = 72;  nt = u - 20;
                           if (WM == 2) { Whi = wsh + OFF_WINTER; Wlo = wsl + OFF_WINTER; } }
        f32x4 acc[2][4];
#pragma unroll
        for (int p = 0; p < 2; p++)
#pragma unroll
            for (int i = 0; i < 4; i++) acc[p][i] = fzero4();
#pragma unroll
        for (int k0 = 0; k0 < OBSD; k0 += 32) {
            const int p = (k0 >> 5) & 1;
            bf16x8 bh, bl;
            loadW<WM>(Wf, Whi, Wlo, OBSD, nt * 16 + lo16, k0 + hi * 8, bh, bl);
            bf16x8 a0 = *(const bf16x8*)(xh + lo16 * 136 + k0 + hi * 8);
            bf16x8 a1 = *(const bf16x8*)(xh + (16 + lo16) * 136 + k0 + hi * 8);
            bf16x8 a2 = *(const bf16x8*)(xh + (32 + lo16) * 136 + k0 + hi * 8);
            bf16x8 a3 = *(const bf16x8*)(xh + (48 + lo16) * 136 + k0 + hi * 8);
            acc[p][0] = MFMA16(a0, bh, acc[p][0]);
            acc[p][1] = MFMA16(a1, bh, acc[p][1]);
            acc[p][2] = MFMA16(a2, bh, acc[p][2]);
            acc[p][3] = MFMA16(a3, bh, acc[p][3]);
            if constexpr (WM == 1) {
                acc[p][0] = MFMA16(a0, bl, acc[p][0]);
                acc[p][1] = MFMA16(a1, bl, acc[p][1]);
                acc[p][2] = MFMA16(a2, bl, acc[p][2]);
                acc[p][3] = MFMA16(a3, bl, acc[p][3]);
            }
            if constexpr (XSPLIT) {
                bf16x8 l0 = *(const bf16x8*)(xl + lo16 * 136 + k0 + hi * 8);
                bf16x8 l1 = *(const bf16x8*)(xl + (16 + lo16) * 136 + k0 + hi * 8);
                bf16x8 l2 = *(const bf16x8*)(xl + (32 + lo16) * 136 + k0 + hi * 8);
                bf16x8 l3 = *(const bf16x8*)(xl + (48 + lo16) * 136 + k0 + hi * 8);
                acc[p][0] = MFMA16(l0, bh, acc[p][0]);
                acc[p][1] = MFMA16(l1, bh, acc[p][1]);
                acc[p][2] = MFMA16(l2, bh, acc[p][2]);
                acc[p][3] = MFMA16(l3, bh, acc[p][3]);
            }
        }
        float bb = tof(bias[nt * 16 + lo16]);
#pragma unroll
        for (int i = 0; i < 4; i++) {
            f32x4 fin = acc[0][i] + acc[1][i];
#pragma unroll
            for (int r = 0; r < 4; r++)
                O[(i * 16 + hi * 4 + r) * ldo + nt * 16 + lo16] = f2b(fast_tanh(fin[r] + bb));
        }
    }
    __syncthreads();

    // ==== P2: 4 MHA nets (0:intra_mu 1:intra_std 2:inter_mu 3:inter_std) ====
#pragma unroll 1
    for (int net = 0; net < 4; net++) {
        qkv_pass<WM>(net, (net < 2) ? intra_e : inter_e, Wqkv, bqkv, wsh, wsl, qk, vT);
        __syncthreads();

        // fused scores + softmax + PV per batch; no LDS P-matrix.
        float epr[2][4] = {{0.f,0.f,0.f,0.f},{0.f,0.f,0.f,0.f}};
        {
            // prefetch eps for std-net outproj (consumed next phase)
            if (net == 1 || net == 3) {
                const T* epsb = ((net == 1) ? eps_intra : eps_inter) + b0 * (AA_ * MSGD);
                const int grp = wv >> 2, col = (wv & 3) * 16 + lo16;
#pragma unroll
                for (int s = 0; s < 2; s++)
#pragma unroll
                    for (int r = 0; r < 4; r++)
                        epr[s][r] = tof(__builtin_nontemporal_load(
                            epsb + (grp * 32 + s * 16 + hi * 4 + r) * MSGD + col));
            }
            const int h = wv >> 1, mt = wv & 1;
#pragma unroll 1
            for (int bt = 0; bt < 2; bt++) {
                const u16* qkB = qk + bt * 32 * 136;
                bf16x8 a0 = *(const bf16x8*)(qkB + lo16 * 136 + 64 + h * 16 + hi * 8);
                bf16x8 a1 = *(const bf16x8*)(qkB + (16 + lo16) * 136 + 64 + h * 16 + hi * 8);
                bf16x8 bq = bzero8();      // zero-pad dh 16->32 (B=0 kills k>=16 terms)
                if (hi < 2) bq = *(const bf16x8*)(qkB + (mt * 16 + lo16) * 136 + h * 16 + hi * 8);
                f32x4 z = fzero4();
                f32x4 sc0 = MFMA16(a0, bq, z);
                f32x4 sc1 = MFMA16(a1, bq, z);
                float v0[4], v1[4];
#pragma unroll
                for (int r = 0; r < 4; r++) { v0[r] = sc0[r] * 0.25f; v1[r] = sc1[r] * 0.25f; }
                float m = fmaxf(fmaxf(fmaxf(v0[0], v0[1]), fmaxf(v0[2], v0[3])),
                                fmaxf(fmaxf(v1[0], v1[1]), fmaxf(v1[2], v1[3])));
                m = fmaxf(m, __shfl_xor(m, 16));
                m = fmaxf(m, __shfl_xor(m, 32));
                float e0[4], e1[4], s = 0.f;
#pragma unroll
                for (int r = 0; r < 4; r++) {
                    e0[r] = __expf(v0[r] - m); e1[r] = __expf(v1[r] - m);
                    s += e0[r] + e1[r];
                }
                s += __shfl_xor(s, 16);
                s += __shfl_xor(s, 32);
                float inv = __builtin_amdgcn_rcpf(s);
                u32 pk0 = (u32)f2b(e0[0] * inv) | ((u32)f2b(e0[1] * inv) << 16);
                u32 pk1 = (u32)f2b(e0[2] * inv) | ((u32)f2b(e0[3] * inv) << 16);
                u32 pk2 = (u32)f2b(e1[0] * inv) | ((u32)f2b(e1[1] * inv) << 16);
                u32 pk3 = (u32)f2b(e1[2] * inv) | ((u32)f2b(e1[3] * inv) << 16);
                const int sA = (((hi * 2) & 3) << 4) | lo16;
                const int sB = sA + 16;
                u32 wA0 = __shfl(pk0, sA), wA1 = __shfl(pk1, sA);
                u32 wB0 = __shfl(pk0, sB), wB1 = __shfl(pk1, sB);
                u32 xA0 = __shfl(pk2, sA), xA1 = __shfl(pk3, sA);
                u32 xB0 = __shfl(pk2, sB), xB1 = __shfl(pk3, sB);
                const bool lo = (hi < 2);
                union { u32 w[4]; bf16x8 v; } pu;
                pu.w[0] = lo ? wA0 : xA0;
                pu.w[1] = lo ? wA1 : xA1;
                pu.w[2] = lo ? wB0 : xB0;
                pu.w[3] = lo ? wB1 : xB1;
                bf16x8 bv_ = *(const bf16x8*)(vT + bt * 2560 + (h * 16 + lo16) * 40 + hi * 8);
                f32x4 o = MFMA16(pu.v, bv_, z);
#pragma unroll
                for (int r = 0; r < 4; r++)
                    atto[(bt * 32 + mt * 16 + hi * 4 + r) * 72 + h * 16 + lo16] = f2b(o[r]);
            }
        }
        __syncthreads();

        // out projection: wave -> (ntU = n-tile, grp = batch). K=64 -> parity chains of 1.
        {
            const T* Won = Wo + (size_t)net * MSGD * MSGD;
            const T* bon = bo + (size_t)net * MSGD;
            const u16* Ohi = (WM == 2) ? wsh + OFF_WO + net * 4096 : nullptr;
            const u16* Olo = (WM == 2) ? wsl + OFF_WO + net * 4096 : nullptr;
            const int ntU = wv & 3, grp = wv >> 2, col = ntU * 16 + lo16;
            f32x4 acc[2][2];
#pragma unroll
            for (int p = 0; p < 2; p++) { acc[p][0] = fzero4(); acc[p][1] = fzero4(); }
#pragma unroll
            for (int k0 = 0; k0 < 64; k0 += 32) {
                const int p = (k0 >> 5) & 1;
                bf16x8 bh, bl;
                loadW<WM>(Won, Ohi, Olo, 64, col, k0 + hi * 8, bh, bl);
                bf16x8 aA = *(const bf16x8*)(atto + (grp * 32 + lo16) * 72 + k0 + hi * 8);
                bf16x8 aB = *(const bf16x8*)(atto + (grp * 32 + 16 + lo16) * 72 + k0 + hi * 8);
                acc[p][0] = MFMA16(aA, bh, acc[p][0]);
                acc[p][1] = MFMA16(aB, bh, acc[p][1]);
                if constexpr (WM == 1) {
                    acc[p][0] = MFMA16(aA, bl, acc[p][0]);
                    acc[p][1] = MFMA16(aB, bl, acc[p][1]);
                }
            }
            float bb = tof(bon[col]);
            u16* tgt = (net < 2) ? iobs : nobs;
#pragma unroll
            for (int s = 0; s < 2; s++) {
                f32x4 acf = acc[0][s] + acc[1][s];
#pragma unroll
                for (int r = 0; r < 4; r++) {
                    const int row = grp * 32 + s * 16 + hi * 4 + r;
                    if (net == 0 || net == 2) {
                        tgt[row * 72 + col] = f2b(acf[r] + bb);
                    } else {
                        float zv = acf[r] + bb - 5.f;
                        float sp = (zv > 20.f) ? zv : __logf(1.f + __expf(zv));
                        tgt[row * 72 + col] = f2b(b2f(tgt[row * 72 + col]) + sp * epr[s][r]);
                    }
                }
            }
        }
        __syncthreads();
    }

    // ---- P3: attention pooling, one wave per batch (wave-synchronous) ----
    if (wv < 2) {
        const int bt = wv;
        if (lane < 32) {
            float acc = tof(att_b[0]);
            const u16* xr = nobs + (bt * 32 + lane) * 72;
#pragma unroll
            for (int j = 0; j < 64; j += 8) {
                bf16x8 x = *(const bf16x8*)(xr + j);
#pragma unroll
                for (int jj = 0; jj < 8; jj++) acc = fmaf(b2f((u16)x[jj]), tof(att_w[j + jj]), acc);
            }
            plog[bt * 32 + lane] = acc;
        }
        __builtin_amdgcn_wave_barrier();
        if (lane < 32) {
            float m = -1e30f;
            for (int a2 = 0; a2 < 32; a2++) m = fmaxf(m, plog[bt * 32 + a2]);
            float s = 0.f;
            for (int a2 = 0; a2 < 32; a2++) s += __expf(plog[bt * 32 + a2] - m);
            pscore[bt * 32 + lane] = __expf(plog[bt * 32 + lane] - m) * __builtin_amdgcn_rcpf(s);
        }
        __builtin_amdgcn_wave_barrier();
        {
            float p = 0.f;
            for (int a2 = 0; a2 < 32; a2++)
                p = fmaf(pscore[bt * 32 + a2], b2f(nobs[(bt * 32 + a2) * 72 + lane]), p);
            u16 h = f2b(p);
            pooled_hi[bt * 64 + lane] = h;
            pooled_lo[bt * 64 + lane] = f2b(p - b2f(h));
        }
    }
    __syncthreads();

    // ---- P4: h = tanh([local | intra_obs | pooled] @ W1^T + b1), M=64 ----
    for (int nt = wv; nt < 16; nt += 8) {
        const int n = nt * 16 + lo16;
        f32x4 acc[2][4];
#pragma unroll
        for (int p = 0; p < 2; p++)
#pragma unroll
            for (int i = 0; i < 4; i++) acc[p][i] = fzero4();
#pragma unroll
        for (int k0 = 0; k0 < 256; k0 += 32) {
            const int p = (k0 >> 5) & 1;
            bf16x8 bh, bl;
            loadW<WM>(W1, WPAIR(OFF_W1), 384, n, k0 + hi * 8, bh, bl);
            bf16x8 a0 = *(const bf16x8*)(localb + lo16 * 264 + k0 + hi * 8);
            bf16x8 a1 = *(const bf16x8*)(localb + (16 + lo16) * 264 + k0 + hi * 8);
            bf16x8 a2 = *(const bf16x8*)(localb + (32 + lo16) * 264 + k0 + hi * 8);
            bf16x8 a3 = *(const bf16x8*)(localb + (48 + lo16) * 264 + k0 + hi * 8);
            acc[p][0] = MFMA16(a0, bh, acc[p][0]);
            acc[p][1] = MFMA16(a1, bh, acc[p][1]);
            acc[p][2] = MFMA16(a2, bh, acc[p][2]);
            acc[p][3] = MFMA16(a3, bh, acc[p][3]);
            if constexpr (WM == 1) {
                acc[p][0] = MFMA16(a0, bl, acc[p][0]); acc[p][1] = MFMA16(a1, bl, acc[p][1]);
                acc[p][2] = MFMA16(a2, bl, acc[p][2]); acc[p][3] = MFMA16(a3, bl, acc[p][3]);
            }
        }
#pragma unroll
        for (int k0 = 0; k0 < 64; k0 += 32) {
            const int p = (k0 >> 5) & 1;
            bf16x8 bh, bl;
            loadW<WM>(W1, WPAIR(OFF_W1), 384, n, 256 + k0 + hi * 8, bh, bl);
            bf16x8 a0 = *(const bf16x8*)(iobs + lo16 * 72 + k0 + hi * 8);
            bf16x8 a1 = *(const bf16x8*)(iobs + (16 + lo16) * 72 + k0 + hi * 8);
            bf16x8 a2 = *(const bf16x8*)(iobs + (32 + lo16) * 72 + k0 + hi * 8);
            bf16x8 a3 = *(const bf16x8*)(iobs + (48 + lo16) * 72 + k0 + hi * 8);
            acc[p][0] = MFMA16(a0, bh, acc[p][0]);
            acc[p][1] = MFMA16(a1, bh, acc[p][1]);
            acc[p][2] = MFMA16(a2, bh, acc[p][2]);
            acc[p][3] = MFMA16(a3, bh, acc[p][3]);
            if constexpr (WM == 1) {
                acc[p][0] = MFMA16(a0, bl, acc[p][0]); acc[p][1] = MFMA16(a1, bl, acc[p][1]);
                acc[p][2] = MFMA16(a2, bl, acc[p][2]); acc[p][3] = MFMA16(a3, bl, acc[p][3]);
            }
        }
        // pooled segment: per-batch broadcast MFMA; hi/lo streams as独立 chains
        f32x4 aph[2], apl[2];
        aph[0] = fzero4(); aph[1] = fzero4(); apl[0] = fzero4(); apl[1] = fzero4();
#pragma unroll
        for (int k0 = 0; k0 < 64; k0 += 32) {
            bf16x8 bh, bl;
            loadW<WM>(W1, WPAIR(OFF_W1), 384, n, 320 + k0 + hi * 8, bh, bl);
            bf16x8 pa0  = *(const bf16x8*)(pooled_hi + k0 + hi * 8);
            bf16x8 pal0 = *(const bf16x8*)(pooled_lo + k0 + hi * 8);
            bf16x8 pa1  = *(const bf16x8*)(pooled_hi + 64 + k0 + hi * 8);
            bf16x8 pal1 = *(const bf16x8*)(pooled_lo + 64 + k0 + hi * 8);
            aph[0] = MFMA16(pa0, bh, aph[0]);
            apl[0] = MFMA16(pal0, bh, apl[0]);
            aph[1] = MFMA16(pa1, bh, aph[1]);
            apl[1] = MFMA16(pal1, bh, apl[1]);
            if constexpr (WM == 1) {
                aph[0] = MFMA16(pa0, bl, aph[0]);
                aph[1] = MFMA16(pa1, bl, aph[1]);
            }
        }
        float bb0 = tof(b1[n]) + aph[0][0] + apl[0][0];
        float bb1 = tof(b1[n]) + aph[1][0] + apl[1][0];
#pragma unroll
        for (int i = 0; i < 4; i++) {
            f32x4 fin = acc[0][i] + acc[1][i];
            const float bb = (i < 2) ? bb0 : bb1;
#pragma unroll
            for (int r = 0; r < 4; r++)
                hb[(i * 16 + hi * 4 + r) * 264 + n] = f2b(fast_tanh(fin[r] + bb));
        }
    }
    __syncthreads();

    // ---- P5: h2 = tanh(h @ W2^T + b2)  (h2 overlays localb; local is dead) ----
    mdense64<256, 256, 1, WM>(hb, 264, W2, WPAIR(OFF_W2), b2, localb, 264);
    __syncthreads();

    // ---- P6: heads ----
    if constexpr (WM == 2) {
        // augmented head [32][256]: rows 0-15 Wa, 16 Wv, 17-31 zero. 8 units = 8 waves.
        const int ntU = wv & 1, rg = wv >> 1;   // rg: 16-row group of h2 (0..3)
        const u16* Hhi = wsh + OFF_WHEAD;
        f32x4 acc[2];
        acc[0] = fzero4(); acc[1] = fzero4();
#pragma unroll
        for (int k0 = 0; k0 < 256; k0 += 32) {
            const int p = (k0 >> 5) & 1;
            bf16x8 bh = *(const bf16x8*)(Hhi + (size_t)(ntU * 16 + lo16) * 256 + k0 + hi * 8);
            bf16x8 a = *(const bf16x8*)(localb + (rg * 16 + lo16) * 264 + k0 + hi * 8);
            acc[p] = MFMA16(a, bh, acc[p]);
        }
        f32x4 fin = acc[0] + acc[1];
#pragma unroll
        for (int r = 0; r < 4; r++) {
            const int row = rg * 16 + hi * 4 + r;
            if (ntU == 0) alog[row * 18 + lo16] = fin[r] + tof(ba[lo16]);
            else if (lo16 == 0) out_v[b0 * 32 + row] = fromf<T>(fin[r] + tof(bv[0]));
        }
    } else {
        if (wv < 2) {           // Wa logits, 32 rows per wave
            f32x4 acc[2][2];
#pragma unroll
            for (int p = 0; p < 2; p++) { acc[p][0] = fzero4(); acc[p][1] = fzero4(); }
#pragma unroll
            for (int k0 = 0; k0 < 256; k0 += 32) {
                const int p = (k0 >> 5) & 1;
                bf16x8 bh, bl;
                loadW<WM>(Wa, nullptr, nullptr, 256, lo16, k0 + hi * 8, bh, bl);
                bf16x8 a0 = *(const bf16x8*)(localb + (wv * 32 + lo16) * 264 + k0 + hi * 8);
                bf16x8 a1 = *(const bf16x8*)(localb + (wv * 32 + 16 + lo16) * 264 + k0 + hi * 8);
                acc[p][0] = MFMA16(a0, bh, acc[p][0]);
                acc[p][1] = MFMA16(a1, bh, acc[p][1]);
                if constexpr (WM == 1) {
                    acc[p][0] = MFMA16(a0, bl, acc[p][0]);
                    acc[p][1] = MFMA16(a1, bl, acc[p][1]);
                }
            }
            f32x4 f0 = acc[0][0] + acc[1][0];
            f32x4 f1 = acc[0][1] + acc[1][1];
            float bb = tof(ba[lo16]);
#pragma unroll
            for (int r = 0; r < 4; r++) {
                alog[(wv * 32 + hi * 4 + r) * 18 + lo16] = f0[r] + bb;
                alog[(wv * 32 + 16 + hi * 4 + r) * 18 + lo16] = f1[r] + bb;
            }
        } else if (wv < 4 && lane < 32) {   // value head rows (wv-2)*32+lane
            const int row = (wv - 2) * 32 + lane;
            const u16* xr = localb + row * 264;
            float acc = tof(bv[0]);
            for (int k0 = 0; k0 < 256; k0 += 8) {
                bf16x8 x = *(const bf16x8*)(xr + k0);
#pragma unroll
                for (int j = 0; j < 8; j++) acc = fmaf(b2f((u16)x[j]), tof(Wv[k0 + j]), acc);
            }
            out_v[b0 * 32 + row] = fromf<T>(acc);
        }
    }
    __syncthreads();
    if (tid < 64) {         // log-softmax + packed store, 64 rows
        const float* lr = alog + tid * 18;
        float m = -1e30f;
#pragma unroll
        for (int n = 0; n < 16; n++) m = fmaxf(m, lr[n]);
        float s = 0.f;
#pragma unroll
        for (int n = 0; n < 16; n++) s += __expf(lr[n] - m);
        float lse = m + __logf(s);
        if constexpr (sizeof(T) == 2) {
            bf16x8 o0, o1;
#pragma unroll
            for (int n = 0; n < 8; n++) {
                o0[n] = (short)f2b(lr[n] - lse);
                o1[n] = (short)f2b(lr[8 + n] - lse);
            }
            bf16x8* oa = (bf16x8*)((u16*)out_a + (b0 * 32 + tid) * 16);
            oa[0] = o0; oa[1] = o1;
        } else {
            float* oa = (float*)out_a + (b0 * 32 + tid) * 16;
#pragma unroll
            for (int g = 0; g < 4; g++) {
                f32x4 t = {lr[4 * g] - lse, lr[4 * g + 1] - lse,
                           lr[4 * g + 2] - lse, lr[4 * g + 3] - lse};
                *(f32x4*)(oa + 4 * g) = t;
            }
        }
    }
#undef WPAIR
}

// dtype detect: fp32 misread as bf16 has uniform-random low halfwords -> some
// exponent field >= 0x90 among the first 64 halfwords w.p. ~1-1e-8.
__device__ __forceinline__ int detect_f32(const void* obs) {
    const unsigned short* u = (const unsigned short*)obs;
    int e = ((int)u[threadIdx.x & 63] >> 7) & 0xFF;
    return __ballot(e >= 0x90) != 0ull;
}

// prep: split all MFMA weights f32 -> bf16 hi/lo into workspace (f32 inputs only).
extern "C" __global__ void TeamCommAgent_prep_kernel(
    const void* obs, const void* Wl, const void* Wi, const void* Wt,
    const void* Wq, const void* Wo_, const void* W1_, const void* W2_,
    const void* Wa_, const void* Wv_, u16* ws) {
    if (!detect_f32(obs)) return;
    int i = blockIdx.x * blockDim.x + threadIdx.x;
    if (i >= WS_TOTAL) return;
    float w;
    if (i >= OFF_WHEAD) {
        int local = i - OFF_WHEAD, row = local >> 8, col = local & 255;
        w = (row < 16) ? ((const float*)Wa_)[row * 256 + col]
          : (row == 16) ? ((const float*)Wv_)[col] : 0.f;
    } else {
        const float* src; int off;
        if (i < OFF_WINTER)      { src = (const float*)Wl;  off = OFF_WLOCAL; }
        else if (i < OFF_WINTRA) { src = (const float*)Wi;  off = OFF_WINTER; }
        else if (i < OFF_WQKV)   { src = (const float*)Wt;  off = OFF_WINTRA; }
        else if (i < OFF_WO)     { src = (const float*)Wq;  off = OFF_WQKV; }
        else if (i < OFF_W1)     { src = (const float*)Wo_; off = OFF_WO; }
        else if (i < OFF_W2)     { src = (const float*)W1_; off = OFF_W1; }
        else if (i < OFF_WA)     { src = (const float*)W2_; off = OFF_W2; }
        else                     { src = (const float*)Wa_; off = OFF_WA; }
        w = src[i - off];
    }
    u16 h = f2b(w);
    ws[i] = h;
    ws[WS_TOTAL + i] = f2b(w - b2f(h));
}

extern "C" __global__ void __launch_bounds__(NT, 2)
TeamCommAgent_53077205844655_kernel(
    const void* obs, const void* eps_intra, const void* eps_inter,
    const void* W_local, const void* b_local,
    const void* W_inter, const void* b_inter,
    const void* W_intra, const void* b_intra,
    const void* Wqkv, const void* bqkv, const void* Wo, const void* bo,
    const void* att_w, const void* att_b,
    const void* W1, const void* b1, const void* W2, const void* b2,
    const void* Wa, const void* ba, const void* Wv, const void* bv,
    void* out, const u16* wsw) {
    __shared__ __align__(16) char smem[SMEM_SZ];
    if (detect_f32(obs)) {
        if (wsw) {
            body<float, 2>((const float*)obs, (const float*)eps_intra, (const float*)eps_inter,
                           (const float*)W_local, (const float*)b_local,
                           (const float*)W_inter, (const float*)b_inter,
                           (const float*)W_intra, (const float*)b_intra,
                           (const float*)Wqkv, (const float*)bqkv,
                           (const float*)Wo, (const float*)bo,
                           (const float*)att_w, (const float*)att_b,
                           (const float*)W1, (const float*)b1,
                           (const float*)W2, (const float*)b2,
                           (const float*)Wa, (const float*)ba,
                           (const float*)Wv, (const float*)bv,
                           (float*)out, (float*)out + (size_t)BB * AA_ * NACTD, smem, wsw);
        } else {
            body<float, 1>((const float*)obs, (const float*)eps_intra, (const float*)eps_inter,
                           (const float*)W_local, (const float*)b_local,
                           (const float*)W_inter, (const float*)b_inter,
                           (const float*)W_intra, (const float*)b_intra,
                           (const float*)Wqkv, (const float*)bqkv,
                           (const float*)Wo, (const float*)bo,
                           (const float*)att_w, (const float*)att_b,
                           (const float*)W1, (const float*)b1,
                           (const float*)W2, (const float*)b2,
                           (const float*)Wa, (const float*)ba,
                           (const float*)Wv, (const float*)bv,
                           (float*)out, (float*)out + (size_t)BB * AA_ * NACTD, smem, nullptr);
        }
    } else {
        body<u16, 0>((const u16*)obs, (const u16*)eps_intra, (const u16*)eps_inter,
                     (const u16*)W_local, (const u16*)b_local,
                     (const u16*)W_inter, (const u16*)b_inter,
                     (const u16*)W_intra, (const u16*)b_intra,
                     (const u16*)Wqkv, (const u16*)bqkv,
                     (const u16*)Wo, (const u16*)bo,
                     (const u16*)att_w, (const u16*)att_b,
                     (const u16*)W1, (const u16*)b1,
                     (const u16*)W2, (const u16*)b2,
                     (const u16*)Wa, (const u16*)ba,
                     (const u16*)Wv, (const u16*)bv,
                     (u16*)out, (u16*)out + (size_t)BB * AA_ * NACTD, smem, nullptr);
    }
}

extern "C" void kernel_launch(void* const* d_in, const int* in_sizes, int n_in,
                              void* d_out, int out_size, void* d_ws, size_t ws_size,
                              hipStream_t stream) {
    const bool use_ws = (d_ws != nullptr) &&
                        (ws_size >= (size_t)(2 * WS_TOTAL) * sizeof(u16));
    if (use_ws) {
        TeamCommAgent_prep_kernel<<<dim3((WS_TOTAL + 255) / 256), dim3(256), 0, stream>>>(
            d_in[0], d_in[3], d_in[5], d_in[7], d_in[9], d_in[11],
            d_in[15], d_in[17], d_in[19], d_in[21], (u16*)d_ws);
    }
    TeamCommAgent_53077205844655_kernel<<<dim3(BB / 2), dim3(NT), 0, stream>>>(
        d_in[0], d_in[1], d_in[2], d_in[3], d_in[4], d_in[5], d_in[6],
        d_in[7], d_in[8], d_in[9], d_in[10], d_in[11], d_in[12], d_in[13],
        d_in[14], d_in[15], d_in[16], d_in[17], d_in[18], d_in[19], d_in[20],
        d_in[21], d_in[22], d_out, use_ws ? (const u16*)d_ws : nullptr);
}